// Round 9
// baseline (777.909 us; speedup 1.0000x reference)
//
#include <hip/hip_runtime.h>
#include <hip/hip_bf16.h>

// Problem constants (match reference setup_inputs)
constexpr int N_NODES = 100000;
constexpr int N_EDGES = 20000;
constexpr int NNZ     = 3200000;
constexpr int F_IN    = 512;
constexpr int HID     = 64;
constexpr int CLS     = 70;

// CSR build via two-level counting sort (round-2/5 validated path:
// both directions built independently from the raw hidx input).
constexpr int CHUNK = 32768;                         // entries per partition block
constexpr int NBA   = (NNZ + CHUNK - 1) / CHUNK;     // 98 partition blocks
// DIR 0: key = edge (15b), val = node (17b), 64 keys/bucket  -> 313 buckets
// DIR 1: key = node (17b), val = edge (15b), 128 keys/bucket -> 782 buckets
constexpr int NBUK0 = (N_EDGES + 63) / 64;           // 313
constexpr int NBUK1 = (N_NODES + 127) / 128;         // 782
constexpr int NH0   = NBUK0 * NBA;                   // 30674
constexpr int NH1   = NBUK1 * NBA;                   // 76636

// ---------------------------------------------------------------------------
// Pass A1: per-block LDS histogram over buckets (raw input)
// ---------------------------------------------------------------------------
template <int DIR>
__global__ __launch_bounds__(256) void part_hist(const int* __restrict__ hidx,
                                                 int* __restrict__ hist) {
    constexpr int NBUK = DIR ? NBUK1 : NBUK0;
    constexpr int KSH  = DIR ? 7 : 6;
    __shared__ int cnt[NBUK];
    for (int b = threadIdx.x; b < NBUK; b += 256) cnt[b] = 0;
    __syncthreads();
    int base = blockIdx.x * CHUNK;
    int lim = NNZ - base; if (lim > CHUNK) lim = CHUNK;
    for (int i = threadIdx.x; i < lim; i += 256) {
        int key = DIR ? hidx[base + i] : hidx[NNZ + base + i];
        atomicAdd(&cnt[key >> KSH], 1);
    }
    __syncthreads();
    for (int b = threadIdx.x; b < NBUK; b += 256)
        hist[b * NBA + blockIdx.x] = cnt[b];
}

// ---------------------------------------------------------------------------
// Generic exclusive scan over n ints: scan_blocks -> scan_bsums -> scan_apply
// ---------------------------------------------------------------------------
__global__ __launch_bounds__(256) void scan_blocks(const int* __restrict__ in,
                                                   int* __restrict__ out,
                                                   int* __restrict__ bsum, int n) {
    __shared__ int tmp[256];
    int base = blockIdx.x * 2048;
    int vals[8];
    int s = 0;
#pragma unroll
    for (int i = 0; i < 8; ++i) {
        int g = base + threadIdx.x * 8 + i;
        int v = (g < n) ? in[g] : 0;
        s += v;
        vals[i] = s;
    }
    tmp[threadIdx.x] = s;
    __syncthreads();
    for (int off = 1; off < 256; off <<= 1) {
        int v = 0;
        if (threadIdx.x >= off) v = tmp[threadIdx.x - off];
        __syncthreads();
        if (threadIdx.x >= off) tmp[threadIdx.x] += v;
        __syncthreads();
    }
    int prev = (threadIdx.x > 0) ? tmp[threadIdx.x - 1] : 0;
#pragma unroll
    for (int i = 0; i < 8; ++i) {
        int g = base + threadIdx.x * 8 + i;
        if (g < n) out[g + 1] = vals[i] + prev;
    }
    if (threadIdx.x == 255) bsum[blockIdx.x] = tmp[255];
}

__global__ __launch_bounds__(64) void scan_bsums(int* __restrict__ bsum, int nb) {
    int t = threadIdx.x;
    int v = (t < nb) ? bsum[t] : 0;
#pragma unroll
    for (int off = 1; off < 64; off <<= 1) {
        int u = __shfl_up(v, off);
        if (t >= off) v += u;
    }
    int ex = __shfl_up(v, 1);
    if (t == 0) ex = 0;
    if (t < nb) bsum[t] = ex;
}

__global__ __launch_bounds__(256) void scan_apply(int* __restrict__ out,
                                                  const int* __restrict__ bsum, int n) {
    int g = blockIdx.x * 256 + threadIdx.x;
    if (g >= n) return;
    out[g + 1] += bsum[g >> 11];
    if (g == 0) out[0] = 0;
}

// ---------------------------------------------------------------------------
// Pass A2: scatter packed (key,val) into bucket regions (raw input)
// ---------------------------------------------------------------------------
template <int DIR>
__global__ __launch_bounds__(256) void part_scatter(const int* __restrict__ hidx,
                                                    const int* __restrict__ scanned,
                                                    unsigned* __restrict__ bucketed) {
    constexpr int NBUK = DIR ? NBUK1 : NBUK0;
    constexpr int KSH  = DIR ? 7 : 6;
    __shared__ int cur[NBUK];
    for (int b = threadIdx.x; b < NBUK; b += 256)
        cur[b] = scanned[b * NBA + blockIdx.x];
    __syncthreads();
    int base = blockIdx.x * CHUNK;
    int lim = NNZ - base; if (lim > CHUNK) lim = CHUNK;
    for (int i = threadIdx.x; i < lim; i += 256) {
        int s = hidx[base + i];
        int e = hidx[NNZ + base + i];
        int key = DIR ? s : e;
        unsigned p = DIR ? (((unsigned)s << 15) | (unsigned)e)
                         : (((unsigned)e << 17) | (unsigned)s);
        int pos = atomicAdd(&cur[key >> KSH], 1);
        bucketed[pos] = p;
    }
}

// ---------------------------------------------------------------------------
// Pass B: per-bucket -> final CSR (ptr, inv-degree, list). All LDS atomics.
// ---------------------------------------------------------------------------
template <int DIR>
__global__ __launch_bounds__(256) void bucket_build(const unsigned* __restrict__ bucketed,
                                                    const int* __restrict__ scanned,
                                                    int* __restrict__ ptr_out,
                                                    float* __restrict__ inv_out,
                                                    int* __restrict__ list) {
    constexpr int KB    = DIR ? 128 : 64;
    constexpr int VSH   = DIR ? 15 : 17;
    constexpr unsigned VMASK = DIR ? 0x7FFFu : 0x1FFFFu;
    constexpr int NKEYS = DIR ? N_NODES : N_EDGES;
    __shared__ int kcnt[KB];
    __shared__ int koff[KB + 1];
    __shared__ int kcur[KB];
    int bucket = blockIdx.x;
    int start = scanned[bucket * NBA];
    int end   = scanned[(bucket + 1) * NBA];
    for (int k = threadIdx.x; k < KB; k += 256) kcnt[k] = 0;
    __syncthreads();
    for (int i = start + threadIdx.x; i < end; i += 256) {
        int kl = (int)((bucketed[i] >> VSH) & (unsigned)(KB - 1));
        atomicAdd(&kcnt[kl], 1);
    }
    __syncthreads();
    if (threadIdx.x == 0) {
        int s = 0;
#pragma unroll 8
        for (int k = 0; k < KB; ++k) { koff[k] = s; s += kcnt[k]; }
        koff[KB] = s;
    }
    __syncthreads();
    if (threadIdx.x < KB) {
        int key = bucket * KB + threadIdx.x;
        int base = start + koff[threadIdx.x];
        if (key < NKEYS) {
            ptr_out[key] = base;
            int d = kcnt[threadIdx.x];
            inv_out[key] = (d > 0) ? 1.0f / (float)d : 0.0f;
        }
        kcur[threadIdx.x] = base;
    }
    __syncthreads();
    for (int i = start + threadIdx.x; i < end; i += 256) {
        unsigned p = bucketed[i];
        int kl = (int)((p >> VSH) & (unsigned)(KB - 1));
        int pos = atomicAdd(&kcur[kl], 1);
        list[pos] = (int)(p & VMASK);
    }
}

__global__ void set_tail(int* __restrict__ p1, int* __restrict__ p2) {
    p1[N_EDGES] = NNZ;
    p2[N_NODES] = NNZ;
}

// ---------------------------------------------------------------------------
// GEMM1: C[M][64] = A[M][512] @ B[512][64]  (fp32)
// BM=64, BK=32, 256 threads, acc[4][4]/thread. Occupancy-first design:
// LDS = A(64x36) + B(32x68) = 17.9KB -> 8 blocks/CU (32 waves, was 4 blocks
// /31% in R8). A tile row-major so staging is 2x ds_write_b128/thread (R8
// had 16 scalar stores + XOR ALU). Inner loop per 4k: 4x b128 A reads
// (16-lane broadcast, 2-way = free) + 4x b128 B reads + 64 FMA.
// ---------------------------------------------------------------------------
__global__ __launch_bounds__(256, 8) void gemm1_kernel(const float* __restrict__ A,
                                                       const float* __restrict__ B,
                                                       float* __restrict__ C, int M) {
    constexpr int BK = 32;
    __shared__ __align__(16) float Ast[64][BK + 4];   // row-major, stride 36
    __shared__ __align__(16) float Bs[BK][HID + 4];   // k-major, stride 68
    int tid = threadIdx.x;
    int tx = tid & 15;                  // col group (4 cols)
    int ty = tid >> 4;                  // row group (4 rows), 0..15
    int row0 = blockIdx.x * 64;
    float acc[4][4] = {};
    int a_row = tid >> 3;               // 0..31 (two row-halves via l)
    int a_c4  = (tid & 7) * 4;          // k offset within tile
    int b_k   = tid >> 4;               // 0..15 (two k-halves via l)
    int b_c   = (tid & 15) * 4;
    for (int k0 = 0; k0 < F_IN; k0 += BK) {
        // stage A: 64 rows x 32 k = 512 float4, 2 per thread (b128 stores)
#pragma unroll
        for (int l = 0; l < 2; ++l) {
            int row = a_row + 32 * l;
            int grow = row0 + row;
            float4 v = make_float4(0.f, 0.f, 0.f, 0.f);
            if (grow < M) v = *reinterpret_cast<const float4*>(&A[(size_t)grow * F_IN + k0 + a_c4]);
            *reinterpret_cast<float4*>(&Ast[row][a_c4]) = v;
        }
        // stage B: 32 k x 64 cols = 512 float4, 2 per thread
#pragma unroll
        for (int l = 0; l < 2; ++l) {
            int k = b_k + 16 * l;
            float4 w = *reinterpret_cast<const float4*>(&B[(size_t)(k0 + k) * HID + b_c]);
            *reinterpret_cast<float4*>(&Bs[k][b_c]) = w;
        }
        __syncthreads();
#pragma unroll
        for (int k = 0; k < BK; k += 4) {
            float4 a0 = *reinterpret_cast<const float4*>(&Ast[ty * 4 + 0][k]);
            float4 a1 = *reinterpret_cast<const float4*>(&Ast[ty * 4 + 1][k]);
            float4 a2 = *reinterpret_cast<const float4*>(&Ast[ty * 4 + 2][k]);
            float4 a3 = *reinterpret_cast<const float4*>(&Ast[ty * 4 + 3][k]);
            float4 b0 = *reinterpret_cast<const float4*>(&Bs[k + 0][tx * 4]);
            float4 b1 = *reinterpret_cast<const float4*>(&Bs[k + 1][tx * 4]);
            float4 b2 = *reinterpret_cast<const float4*>(&Bs[k + 2][tx * 4]);
            float4 b3 = *reinterpret_cast<const float4*>(&Bs[k + 3][tx * 4]);
            float a[4][4] = {{a0.x, a0.y, a0.z, a0.w},
                             {a1.x, a1.y, a1.z, a1.w},
                             {a2.x, a2.y, a2.z, a2.w},
                             {a3.x, a3.y, a3.z, a3.w}};
            float b[4][4] = {{b0.x, b0.y, b0.z, b0.w},
                             {b1.x, b1.y, b1.z, b1.w},
                             {b2.x, b2.y, b2.z, b2.w},
                             {b3.x, b3.y, b3.z, b3.w}};
#pragma unroll
            for (int s = 0; s < 4; ++s)
#pragma unroll
                for (int i = 0; i < 4; ++i)
#pragma unroll
                    for (int j = 0; j < 4; ++j)
                        acc[i][j] += a[i][s] * b[s][j];
        }
        __syncthreads();
    }
#pragma unroll
    for (int i = 0; i < 4; ++i) {
        int row = row0 + ty * 4 + i;
        if (row < M) {
            float4 v = make_float4(acc[i][0], acc[i][1], acc[i][2], acc[i][3]);
            *reinterpret_cast<float4*>(&C[(size_t)row * HID + tx * 4]) = v;
        }
    }
}

// ---------------------------------------------------------------------------
// Segment gather-sum, MLP version: wave per segment; 4 groups of 16 lanes;
// group g fetches row list[...+g] as 16 x float4 (256B); up to 16 independent
// row-gathers in flight per wave. ALL shuffles executed uniformly by all 64
// lanes; remainder handled with a clamped source lane (always valid).
// ---------------------------------------------------------------------------
__global__ __launch_bounds__(256) void seg_gather(const float* __restrict__ in,
                                                  float* __restrict__ out,
                                                  const int* __restrict__ ptr,
                                                  const int* __restrict__ list,
                                                  const float* __restrict__ scale,
                                                  const float* __restrict__ bias,
                                                  int nseg, int do_relu) {
    int gid = blockIdx.x * 256 + threadIdx.x;
    int seg = gid >> 6;
    int lane = gid & 63;
    if (seg >= nseg) return;
    int beg = ptr[seg], end = ptr[seg + 1];
    int g = lane >> 4, sub = lane & 15;
    const float4* in4 = reinterpret_cast<const float4*>(in);
    float4 acc = make_float4(0.f, 0.f, 0.f, 0.f);
    for (int j = beg; j < end; j += 64) {
        int cnt = end - j; if (cnt > 64) cnt = 64;       // wave-uniform
        int idx = (lane < cnt) ? list[j + lane] : 0;
        int full16 = cnt >> 4;                            // uniform
        for (int s = 0; s < full16; ++s) {                // all lanes active
            int r0 = 16 * s + g;
            int n0 = __shfl(idx, r0);
            int n1 = __shfl(idx, r0 + 4);
            int n2 = __shfl(idx, r0 + 8);
            int n3 = __shfl(idx, r0 + 12);
            float4 v0 = in4[(size_t)n0 * 16 + sub];
            float4 v1 = in4[(size_t)n1 * 16 + sub];
            float4 v2 = in4[(size_t)n2 * 16 + sub];
            float4 v3 = in4[(size_t)n3 * 16 + sub];
            acc.x += (v0.x + v1.x) + (v2.x + v3.x);
            acc.y += (v0.y + v1.y) + (v2.y + v3.y);
            acc.z += (v0.z + v1.z) + (v2.z + v3.z);
            acc.w += (v0.w + v1.w) + (v2.w + v3.w);
        }
        int rem_start = full16 << 4;
        int nrem4 = (cnt - rem_start + 3) >> 2;           // 0..4, uniform
        for (int t = 0; t < nrem4; ++t) {                 // uniform trip count
            int row = rem_start + 4 * t + g;
            int n = __shfl(idx, row < cnt ? row : 0);     // clamped src, defined
            if (row < cnt) {
                float4 v = in4[(size_t)n * 16 + sub];
                acc.x += v.x; acc.y += v.y; acc.z += v.z; acc.w += v.w;
            }
        }
    }
    acc.x += __shfl_xor(acc.x, 16);
    acc.y += __shfl_xor(acc.y, 16);
    acc.z += __shfl_xor(acc.z, 16);
    acc.w += __shfl_xor(acc.w, 16);
    acc.x += __shfl_xor(acc.x, 32);
    acc.y += __shfl_xor(acc.y, 32);
    acc.z += __shfl_xor(acc.z, 32);
    acc.w += __shfl_xor(acc.w, 32);
    if (lane < 16) {
        float s = scale[seg];
        acc.x *= s; acc.y *= s; acc.z *= s; acc.w *= s;
        if (bias) {
            float4 b = reinterpret_cast<const float4*>(bias)[sub];
            acc.x += b.x; acc.y += b.y; acc.z += b.z; acc.w += b.w;
        }
        if (do_relu) {
            acc.x = fmaxf(acc.x, 0.f); acc.y = fmaxf(acc.y, 0.f);
            acc.z = fmaxf(acc.z, 0.f); acc.w = fmaxf(acc.w, 0.f);
        }
        reinterpret_cast<float4*>(out)[(size_t)seg * 16 + sub] = acc;
    }
}

// ---------------------------------------------------------------------------
// GEMM2 epilogue: out[M][70] = in[M][64] @ W2[64][70] + b2  (wave per row)
// ---------------------------------------------------------------------------
__global__ __launch_bounds__(256) void gemm2_kernel(const float* __restrict__ in,
                                                    const float* __restrict__ W2,
                                                    const float* __restrict__ b2,
                                                    float* __restrict__ out, int M) {
    __shared__ float Ws[HID][72];
    __shared__ float bs[72];
    __shared__ float rows[4][HID];
    int tid = threadIdx.x;
    for (int i = tid; i < HID * 72; i += 256) {
        int r = i / 72, c = i % 72;
        Ws[r][c] = (c < CLS) ? W2[r * CLS + c] : 0.f;
    }
    if (tid < 72) bs[tid] = (tid < CLS) ? b2[tid] : 0.f;
    int wid = tid >> 6, lane = tid & 63;
    int m = blockIdx.x * 4 + wid;
    if (m < M) rows[wid][lane] = in[(size_t)m * HID + lane];
    __syncthreads();
    if (m >= M) return;
    int c2 = 64 + (lane & 7);
    float acc0 = bs[lane];
    float acc1 = bs[c2];
#pragma unroll
    for (int k = 0; k < HID; ++k) {
        float xv = rows[wid][k];
        acc0 += xv * Ws[k][lane];
        acc1 += xv * Ws[k][c2];
    }
    out[(size_t)m * CLS + lane] = acc0;
    if (lane < 6) out[(size_t)m * CLS + 64 + lane] = acc1;
}

// ---------------------------------------------------------------------------
extern "C" void kernel_launch(void* const* d_in, const int* in_sizes, int n_in,
                              void* d_out, int out_size, void* d_ws, size_t ws_size,
                              hipStream_t stream) {
    const float* x   = (const float*)d_in[0];
    const int*   hid = (const int*)d_in[1];     // [2][NNZ] int32: row0=node, row1=edge
    const float* W1  = (const float*)d_in[2];
    const float* b1  = (const float*)d_in[3];
    const float* W2  = (const float*)d_in[4];
    const float* b2  = (const float*)d_in[5];
    float* out = (float*)d_out;

    size_t off = 0;
    auto alloc = [&](size_t bytes) {
        void* p = (char*)d_ws + off;
        off += (bytes + 255) & ~(size_t)255;
        return p;
    };
    int*   ptr1  = (int*)alloc((size_t)(N_EDGES + 1) * 4);
    int*   ptr2  = (int*)alloc((size_t)(N_NODES + 1) * 4);
    int*   bsum  = (int*)alloc(64 * 4);
    float* Binv  = (float*)alloc((size_t)N_EDGES * 4);
    float* Dinv  = (float*)alloc((size_t)N_NODES * 4);
    int*   list1 = (int*)alloc((size_t)NNZ * 4);
    int*   list2 = (int*)alloc((size_t)NNZ * 4);
    float* bufA  = (float*)alloc((size_t)N_NODES * HID * 4);   // xW1, later agg2
    float* bufB  = (float*)alloc((size_t)N_NODES * HID * 4);   // h1 (relu'd)
    float* he    = (float*)alloc((size_t)N_EDGES * HID * 4);   // edge features
    (void)ws_size; (void)n_in; (void)in_sizes; (void)out_size;

    // Build-time scratch aliases (regions only written after the build)
    int*      hist     = (int*)he;                             // <= 307KB
    int*      scanned  = (int*)((char*)he + (512 << 10));      // <= 307KB
    unsigned* bucketed = (unsigned*)bufB;                      // 12.8MB

    // ---- build direction 0 (by edge): ptr1/list1/Binv ----
    part_hist<0><<<NBA, 256, 0, stream>>>(hid, hist);
    scan_blocks<<<(NH0 + 2047) / 2048, 256, 0, stream>>>(hist, scanned, bsum, NH0);
    scan_bsums<<<1, 64, 0, stream>>>(bsum, (NH0 + 2047) / 2048);
    scan_apply<<<(NH0 + 255) / 256, 256, 0, stream>>>(scanned, bsum, NH0);
    part_scatter<0><<<NBA, 256, 0, stream>>>(hid, scanned, bucketed);
    bucket_build<0><<<NBUK0, 256, 0, stream>>>(bucketed, scanned, ptr1, Binv, list1);

    // ---- build direction 1 (by node): ptr2/list2/Dinv ----
    part_hist<1><<<NBA, 256, 0, stream>>>(hid, hist);
    scan_blocks<<<(NH1 + 2047) / 2048, 256, 0, stream>>>(hist, scanned, bsum, NH1);
    scan_bsums<<<1, 64, 0, stream>>>(bsum, (NH1 + 2047) / 2048);
    scan_apply<<<(NH1 + 255) / 256, 256, 0, stream>>>(scanned, bsum, NH1);
    part_scatter<1><<<NBA, 256, 0, stream>>>(hid, scanned, bucketed);
    bucket_build<1><<<NBUK1, 256, 0, stream>>>(bucketed, scanned, ptr2, Dinv, list2);

    set_tail<<<1, 1, 0, stream>>>(ptr1, ptr2);

    // Layer 1: xW1 -> edge agg -> node agg (+b1, relu)
    gemm1_kernel<<<(N_NODES + 63) / 64, 256, 0, stream>>>(x, W1, bufA, N_NODES);
    seg_gather<<<(N_EDGES * 64) / 256, 256, 0, stream>>>(bufA, he, ptr1, list1, Binv, nullptr, N_EDGES, 0);
    seg_gather<<<(N_NODES * 64) / 256, 256, 0, stream>>>(he, bufB, ptr2, list2, Dinv, b1, N_NODES, 1);

    // Layer 2: edge agg -> node agg, then @W2 + b2 (associativity: A(hW2)=(Ah)W2)
    seg_gather<<<(N_EDGES * 64) / 256, 256, 0, stream>>>(bufB, he, ptr1, list1, Binv, nullptr, N_EDGES, 0);
    seg_gather<<<(N_NODES * 64) / 256, 256, 0, stream>>>(he, bufA, ptr2, list2, Dinv, nullptr, N_NODES, 0);
    gemm2_kernel<<<(N_NODES + 3) / 4, 256, 0, stream>>>(bufA, W2, b2, out, N_NODES);
}

// Round 10
// 709.205 us; speedup vs baseline: 1.0969x; 1.0969x over previous
//
#include <hip/hip_runtime.h>
#include <hip/hip_bf16.h>

// Problem constants (match reference setup_inputs)
constexpr int N_NODES = 100000;
constexpr int N_EDGES = 20000;
constexpr int NNZ     = 3200000;
constexpr int F_IN    = 512;
constexpr int HID     = 64;
constexpr int CLS     = 70;

// CSR build via two-level counting sort, both directions fused:
// one histogram pass + one concatenated scan + one fused scatter.
constexpr int CHUNK = 32768;                         // entries per partition block
constexpr int NBA   = (NNZ + CHUNK - 1) / CHUNK;     // 98 partition blocks
// DIR 0: key = edge (15b), val = node (17b), 64 keys/bucket  -> 313 buckets
// DIR 1: key = node (17b), val = edge (15b), 128 keys/bucket -> 782 buckets
constexpr int NBUK0 = (N_EDGES + 63) / 64;           // 313
constexpr int NBUK1 = (N_NODES + 127) / 128;         // 782
constexpr int NH0   = NBUK0 * NBA;                   // 30674
constexpr int NH1   = NBUK1 * NBA;                   // 76636
constexpr int NHT   = NH0 + NH1;                     // 107310 (concatenated)

// ---------------------------------------------------------------------------
// Pass A1 (fused): per-block LDS histograms for BOTH directions, one pass.
// hist layout: dir0 at [b*NBA+blk], dir1 at [NH0 + b*NBA + blk].
// ---------------------------------------------------------------------------
__global__ __launch_bounds__(256) void part_hist_both(const int* __restrict__ hidx,
                                                      int* __restrict__ hist) {
    __shared__ int cnt[NBUK0 + NBUK1];
    for (int b = threadIdx.x; b < NBUK0 + NBUK1; b += 256) cnt[b] = 0;
    __syncthreads();
    int base = blockIdx.x * CHUNK;
    int lim = NNZ - base; if (lim > CHUNK) lim = CHUNK;
    for (int i = threadIdx.x; i < lim; i += 256) {
        int s = hidx[base + i];
        int e = hidx[NNZ + base + i];
        atomicAdd(&cnt[e >> 6], 1);
        atomicAdd(&cnt[NBUK0 + (s >> 7)], 1);
    }
    __syncthreads();
    for (int b = threadIdx.x; b < NBUK0; b += 256)
        hist[b * NBA + blockIdx.x] = cnt[b];
    for (int b = threadIdx.x; b < NBUK1; b += 256)
        hist[NH0 + b * NBA + blockIdx.x] = cnt[NBUK0 + b];
}

// ---------------------------------------------------------------------------
// Generic exclusive scan over n ints: scan_blocks -> scan_bsums -> scan_apply
// (single scan over the concatenated NHT histogram; scanned[NH0] == NNZ, so
// dir1 positions automatically land in [NNZ, 2*NNZ) of the bucketed buffer)
// ---------------------------------------------------------------------------
__global__ __launch_bounds__(256) void scan_blocks(const int* __restrict__ in,
                                                   int* __restrict__ out,
                                                   int* __restrict__ bsum, int n) {
    __shared__ int tmp[256];
    int base = blockIdx.x * 2048;
    int vals[8];
    int s = 0;
#pragma unroll
    for (int i = 0; i < 8; ++i) {
        int g = base + threadIdx.x * 8 + i;
        int v = (g < n) ? in[g] : 0;
        s += v;
        vals[i] = s;
    }
    tmp[threadIdx.x] = s;
    __syncthreads();
    for (int off = 1; off < 256; off <<= 1) {
        int v = 0;
        if (threadIdx.x >= off) v = tmp[threadIdx.x - off];
        __syncthreads();
        if (threadIdx.x >= off) tmp[threadIdx.x] += v;
        __syncthreads();
    }
    int prev = (threadIdx.x > 0) ? tmp[threadIdx.x - 1] : 0;
#pragma unroll
    for (int i = 0; i < 8; ++i) {
        int g = base + threadIdx.x * 8 + i;
        if (g < n) out[g + 1] = vals[i] + prev;
    }
    if (threadIdx.x == 255) bsum[blockIdx.x] = tmp[255];
}

__global__ __launch_bounds__(64) void scan_bsums(int* __restrict__ bsum, int nb) {
    int t = threadIdx.x;
    int v = (t < nb) ? bsum[t] : 0;
#pragma unroll
    for (int off = 1; off < 64; off <<= 1) {
        int u = __shfl_up(v, off);
        if (t >= off) v += u;
    }
    int ex = __shfl_up(v, 1);
    if (t == 0) ex = 0;
    if (t < nb) bsum[t] = ex;
}

__global__ __launch_bounds__(256) void scan_apply(int* __restrict__ out,
                                                  const int* __restrict__ bsum, int n) {
    int g = blockIdx.x * 256 + threadIdx.x;
    if (g >= n) return;
    out[g + 1] += bsum[g >> 11];
    if (g == 0) out[0] = 0;
}

// ---------------------------------------------------------------------------
// Pass A2 (fused): scatter BOTH packed directions in one pass over hidx.
// bucketed[0..NNZ) = dir0 (e<<17|s); bucketed[NNZ..2NNZ) = dir1 (s<<15|e).
// ---------------------------------------------------------------------------
__global__ __launch_bounds__(256) void part_scatter_both(const int* __restrict__ hidx,
                                                         const int* __restrict__ scanned,
                                                         unsigned* __restrict__ bucketed) {
    __shared__ int cur[NBUK0 + NBUK1];
    for (int b = threadIdx.x; b < NBUK0; b += 256)
        cur[b] = scanned[b * NBA + blockIdx.x];
    for (int b = threadIdx.x; b < NBUK1; b += 256)
        cur[NBUK0 + b] = scanned[NH0 + b * NBA + blockIdx.x];
    __syncthreads();
    int base = blockIdx.x * CHUNK;
    int lim = NNZ - base; if (lim > CHUNK) lim = CHUNK;
    for (int i = threadIdx.x; i < lim; i += 256) {
        int s = hidx[base + i];
        int e = hidx[NNZ + base + i];
        int pos0 = atomicAdd(&cur[e >> 6], 1);
        bucketed[pos0] = ((unsigned)e << 17) | (unsigned)s;
        int pos1 = atomicAdd(&cur[NBUK0 + (s >> 7)], 1);
        bucketed[pos1] = ((unsigned)s << 15) | (unsigned)e;
    }
}

// ---------------------------------------------------------------------------
// Pass B: per-bucket -> final CSR (ptr, inv-degree, list). All LDS atomics.
// `sc` points at this direction's histogram scan region; `sub` removes the
// global offset (0 for dir0, NNZ for dir1) from ptr/list positions.
// ---------------------------------------------------------------------------
template <int DIR>
__global__ __launch_bounds__(256) void bucket_build(const unsigned* __restrict__ bucketed,
                                                    const int* __restrict__ sc,
                                                    int* __restrict__ ptr_out,
                                                    float* __restrict__ inv_out,
                                                    int* __restrict__ list, int sub) {
    constexpr int KB    = DIR ? 128 : 64;
    constexpr int VSH   = DIR ? 15 : 17;
    constexpr unsigned VMASK = DIR ? 0x7FFFu : 0x1FFFFu;
    constexpr int NKEYS = DIR ? N_NODES : N_EDGES;
    __shared__ int kcnt[KB];
    __shared__ int koff[KB + 1];
    __shared__ int kcur[KB];
    int bucket = blockIdx.x;
    int start = sc[bucket * NBA];
    int end   = sc[(bucket + 1) * NBA];
    for (int k = threadIdx.x; k < KB; k += 256) kcnt[k] = 0;
    __syncthreads();
    for (int i = start + threadIdx.x; i < end; i += 256) {
        int kl = (int)((bucketed[i] >> VSH) & (unsigned)(KB - 1));
        atomicAdd(&kcnt[kl], 1);
    }
    __syncthreads();
    if (threadIdx.x == 0) {
        int s = 0;
#pragma unroll 8
        for (int k = 0; k < KB; ++k) { koff[k] = s; s += kcnt[k]; }
        koff[KB] = s;
    }
    __syncthreads();
    if (threadIdx.x < KB) {
        int key = bucket * KB + threadIdx.x;
        int base = start + koff[threadIdx.x];
        if (key < NKEYS) {
            ptr_out[key] = base - sub;
            int d = kcnt[threadIdx.x];
            inv_out[key] = (d > 0) ? 1.0f / (float)d : 0.0f;
        }
        kcur[threadIdx.x] = base;
    }
    __syncthreads();
    for (int i = start + threadIdx.x; i < end; i += 256) {
        unsigned p = bucketed[i];
        int kl = (int)((p >> VSH) & (unsigned)(KB - 1));
        int pos = atomicAdd(&kcur[kl], 1);
        list[pos - sub] = (int)(p & VMASK);
    }
}

__global__ void set_tail(int* __restrict__ p1, int* __restrict__ p2) {
    p1[N_EDGES] = NNZ;
    p2[N_NODES] = NNZ;
}

// ---------------------------------------------------------------------------
// GEMM1: C[M][64] = A[M][512] @ B[512][64]  (fp32)  — R9 validated version.
// BM=64, BK=32, 256 threads, acc[4][4]/thread; 17.9KB LDS -> 8 blocks/CU.
// ---------------------------------------------------------------------------
__global__ __launch_bounds__(256, 8) void gemm1_kernel(const float* __restrict__ A,
                                                       const float* __restrict__ B,
                                                       float* __restrict__ C, int M) {
    constexpr int BK = 32;
    __shared__ __align__(16) float Ast[64][BK + 4];   // row-major, stride 36
    __shared__ __align__(16) float Bs[BK][HID + 4];   // k-major, stride 68
    int tid = threadIdx.x;
    int tx = tid & 15;
    int ty = tid >> 4;
    int row0 = blockIdx.x * 64;
    float acc[4][4] = {};
    int a_row = tid >> 3;
    int a_c4  = (tid & 7) * 4;
    int b_k   = tid >> 4;
    int b_c   = (tid & 15) * 4;
    for (int k0 = 0; k0 < F_IN; k0 += BK) {
#pragma unroll
        for (int l = 0; l < 2; ++l) {
            int row = a_row + 32 * l;
            int grow = row0 + row;
            float4 v = make_float4(0.f, 0.f, 0.f, 0.f);
            if (grow < M) v = *reinterpret_cast<const float4*>(&A[(size_t)grow * F_IN + k0 + a_c4]);
            *reinterpret_cast<float4*>(&Ast[row][a_c4]) = v;
        }
#pragma unroll
        for (int l = 0; l < 2; ++l) {
            int k = b_k + 16 * l;
            float4 w = *reinterpret_cast<const float4*>(&B[(size_t)(k0 + k) * HID + b_c]);
            *reinterpret_cast<float4*>(&Bs[k][b_c]) = w;
        }
        __syncthreads();
#pragma unroll
        for (int k = 0; k < BK; k += 4) {
            float4 a0 = *reinterpret_cast<const float4*>(&Ast[ty * 4 + 0][k]);
            float4 a1 = *reinterpret_cast<const float4*>(&Ast[ty * 4 + 1][k]);
            float4 a2 = *reinterpret_cast<const float4*>(&Ast[ty * 4 + 2][k]);
            float4 a3 = *reinterpret_cast<const float4*>(&Ast[ty * 4 + 3][k]);
            float4 b0 = *reinterpret_cast<const float4*>(&Bs[k + 0][tx * 4]);
            float4 b1 = *reinterpret_cast<const float4*>(&Bs[k + 1][tx * 4]);
            float4 b2 = *reinterpret_cast<const float4*>(&Bs[k + 2][tx * 4]);
            float4 b3 = *reinterpret_cast<const float4*>(&Bs[k + 3][tx * 4]);
            float a[4][4] = {{a0.x, a0.y, a0.z, a0.w},
                             {a1.x, a1.y, a1.z, a1.w},
                             {a2.x, a2.y, a2.z, a2.w},
                             {a3.x, a3.y, a3.z, a3.w}};
            float b[4][4] = {{b0.x, b0.y, b0.z, b0.w},
                             {b1.x, b1.y, b1.z, b1.w},
                             {b2.x, b2.y, b2.z, b2.w},
                             {b3.x, b3.y, b3.z, b3.w}};
#pragma unroll
            for (int s = 0; s < 4; ++s)
#pragma unroll
                for (int i = 0; i < 4; ++i)
#pragma unroll
                    for (int j = 0; j < 4; ++j)
                        acc[i][j] += a[i][s] * b[s][j];
        }
        __syncthreads();
    }
#pragma unroll
    for (int i = 0; i < 4; ++i) {
        int row = row0 + ty * 4 + i;
        if (row < M) {
            float4 v = make_float4(acc[i][0], acc[i][1], acc[i][2], acc[i][3]);
            *reinterpret_cast<float4*>(&C[(size_t)row * HID + tx * 4]) = v;
        }
    }
}

// ---------------------------------------------------------------------------
// Segment gather-sum, MLP version: wave per segment; 4 groups of 16 lanes;
// group g fetches row list[...+g] as 16 x float4 (256B). Depth-2 unrolled
// main loop -> 8 outstanding 16B loads/lane = 32 rows in flight per wave
// (accumulation order preserved bit-exactly vs depth-1). PHASE template
// parameter exists only to give each launch a distinct kernel name in the
// profile. ALL shuffles executed uniformly by all 64 lanes.
// ---------------------------------------------------------------------------
template <int PHASE>
__global__ __launch_bounds__(256) void seg_gather(const float* __restrict__ in,
                                                  float* __restrict__ out,
                                                  const int* __restrict__ ptr,
                                                  const int* __restrict__ list,
                                                  const float* __restrict__ scale,
                                                  const float* __restrict__ bias,
                                                  int nseg, int do_relu) {
    int gid = blockIdx.x * 256 + threadIdx.x;
    int seg = gid >> 6;
    int lane = gid & 63;
    if (seg >= nseg) return;
    int beg = ptr[seg], end = ptr[seg + 1];
    int g = lane >> 4, sub = lane & 15;
    const float4* in4 = reinterpret_cast<const float4*>(in);
    float4 acc = make_float4(0.f, 0.f, 0.f, 0.f);
    for (int j = beg; j < end; j += 64) {
        int cnt = end - j; if (cnt > 64) cnt = 64;       // wave-uniform
        int idx = (lane < cnt) ? list[j + lane] : 0;
        int full16 = cnt >> 4;                            // uniform
        int s = 0;
        for (; s + 2 <= full16; s += 2) {                 // 32 rows in flight
            int r0 = 16 * s + g;
            int n0 = __shfl(idx, r0);
            int n1 = __shfl(idx, r0 + 4);
            int n2 = __shfl(idx, r0 + 8);
            int n3 = __shfl(idx, r0 + 12);
            int n4 = __shfl(idx, r0 + 16);
            int n5 = __shfl(idx, r0 + 20);
            int n6 = __shfl(idx, r0 + 24);
            int n7 = __shfl(idx, r0 + 28);
            float4 v0 = in4[(size_t)n0 * 16 + sub];
            float4 v1 = in4[(size_t)n1 * 16 + sub];
            float4 v2 = in4[(size_t)n2 * 16 + sub];
            float4 v3 = in4[(size_t)n3 * 16 + sub];
            float4 v4 = in4[(size_t)n4 * 16 + sub];
            float4 v5 = in4[(size_t)n5 * 16 + sub];
            float4 v6 = in4[(size_t)n6 * 16 + sub];
            float4 v7 = in4[(size_t)n7 * 16 + sub];
            acc.x += (v0.x + v1.x) + (v2.x + v3.x);
            acc.y += (v0.y + v1.y) + (v2.y + v3.y);
            acc.z += (v0.z + v1.z) + (v2.z + v3.z);
            acc.w += (v0.w + v1.w) + (v2.w + v3.w);
            acc.x += (v4.x + v5.x) + (v6.x + v7.x);
            acc.y += (v4.y + v5.y) + (v6.y + v7.y);
            acc.z += (v4.z + v5.z) + (v6.z + v7.z);
            acc.w += (v4.w + v5.w) + (v6.w + v7.w);
        }
        for (; s < full16; ++s) {                         // leftover 16-row iter
            int r0 = 16 * s + g;
            int n0 = __shfl(idx, r0);
            int n1 = __shfl(idx, r0 + 4);
            int n2 = __shfl(idx, r0 + 8);
            int n3 = __shfl(idx, r0 + 12);
            float4 v0 = in4[(size_t)n0 * 16 + sub];
            float4 v1 = in4[(size_t)n1 * 16 + sub];
            float4 v2 = in4[(size_t)n2 * 16 + sub];
            float4 v3 = in4[(size_t)n3 * 16 + sub];
            acc.x += (v0.x + v1.x) + (v2.x + v3.x);
            acc.y += (v0.y + v1.y) + (v2.y + v3.y);
            acc.z += (v0.z + v1.z) + (v2.z + v3.z);
            acc.w += (v0.w + v1.w) + (v2.w + v3.w);
        }
        int rem_start = full16 << 4;
        int nrem4 = (cnt - rem_start + 3) >> 2;           // 0..4, uniform
        for (int t = 0; t < nrem4; ++t) {                 // uniform trip count
            int row = rem_start + 4 * t + g;
            int n = __shfl(idx, row < cnt ? row : 0);     // clamped src, defined
            if (row < cnt) {
                float4 v = in4[(size_t)n * 16 + sub];
                acc.x += v.x; acc.y += v.y; acc.z += v.z; acc.w += v.w;
            }
        }
    }
    acc.x += __shfl_xor(acc.x, 16);
    acc.y += __shfl_xor(acc.y, 16);
    acc.z += __shfl_xor(acc.z, 16);
    acc.w += __shfl_xor(acc.w, 16);
    acc.x += __shfl_xor(acc.x, 32);
    acc.y += __shfl_xor(acc.y, 32);
    acc.z += __shfl_xor(acc.z, 32);
    acc.w += __shfl_xor(acc.w, 32);
    if (lane < 16) {
        float s = scale[seg];
        acc.x *= s; acc.y *= s; acc.z *= s; acc.w *= s;
        if (bias) {
            float4 b = reinterpret_cast<const float4*>(bias)[sub];
            acc.x += b.x; acc.y += b.y; acc.z += b.z; acc.w += b.w;
        }
        if (do_relu) {
            acc.x = fmaxf(acc.x, 0.f); acc.y = fmaxf(acc.y, 0.f);
            acc.z = fmaxf(acc.z, 0.f); acc.w = fmaxf(acc.w, 0.f);
        }
        reinterpret_cast<float4*>(out)[(size_t)seg * 16 + sub] = acc;
    }
}

// ---------------------------------------------------------------------------
// GEMM2 epilogue: out[M][70] = in[M][64] @ W2[64][70] + b2  (wave per row)
// ---------------------------------------------------------------------------
__global__ __launch_bounds__(256) void gemm2_kernel(const float* __restrict__ in,
                                                    const float* __restrict__ W2,
                                                    const float* __restrict__ b2,
                                                    float* __restrict__ out, int M) {
    __shared__ float Ws[HID][72];
    __shared__ float bs[72];
    __shared__ float rows[4][HID];
    int tid = threadIdx.x;
    for (int i = tid; i < HID * 72; i += 256) {
        int r = i / 72, c = i % 72;
        Ws[r][c] = (c < CLS) ? W2[r * CLS + c] : 0.f;
    }
    if (tid < 72) bs[tid] = (tid < CLS) ? b2[tid] : 0.f;
    int wid = tid >> 6, lane = tid & 63;
    int m = blockIdx.x * 4 + wid;
    if (m < M) rows[wid][lane] = in[(size_t)m * HID + lane];
    __syncthreads();
    if (m >= M) return;
    int c2 = 64 + (lane & 7);
    float acc0 = bs[lane];
    float acc1 = bs[c2];
#pragma unroll
    for (int k = 0; k < HID; ++k) {
        float xv = rows[wid][k];
        acc0 += xv * Ws[k][lane];
        acc1 += xv * Ws[k][c2];
    }
    out[(size_t)m * CLS + lane] = acc0;
    if (lane < 6) out[(size_t)m * CLS + 64 + lane] = acc1;
}

// ---------------------------------------------------------------------------
extern "C" void kernel_launch(void* const* d_in, const int* in_sizes, int n_in,
                              void* d_out, int out_size, void* d_ws, size_t ws_size,
                              hipStream_t stream) {
    const float* x   = (const float*)d_in[0];
    const int*   hid = (const int*)d_in[1];     // [2][NNZ] int32: row0=node, row1=edge
    const float* W1  = (const float*)d_in[2];
    const float* b1  = (const float*)d_in[3];
    const float* W2  = (const float*)d_in[4];
    const float* b2  = (const float*)d_in[5];
    float* out = (float*)d_out;

    size_t off = 0;
    auto alloc = [&](size_t bytes) {
        void* p = (char*)d_ws + off;
        off += (bytes + 255) & ~(size_t)255;
        return p;
    };
    int*   ptr1  = (int*)alloc((size_t)(N_EDGES + 1) * 4);
    int*   ptr2  = (int*)alloc((size_t)(N_NODES + 1) * 4);
    int*   bsum  = (int*)alloc(64 * 4);
    float* Binv  = (float*)alloc((size_t)N_EDGES * 4);
    float* Dinv  = (float*)alloc((size_t)N_NODES * 4);
    int*   list1 = (int*)alloc((size_t)NNZ * 4);
    int*   list2 = (int*)alloc((size_t)NNZ * 4);
    float* bufA  = (float*)alloc((size_t)N_NODES * HID * 4);   // xW1, later agg2
    float* bufB  = (float*)alloc((size_t)N_NODES * HID * 4);   // h1 (relu'd)
    float* he    = (float*)alloc((size_t)N_EDGES * HID * 4);   // edge features
    (void)ws_size; (void)n_in; (void)in_sizes; (void)out_size;

    // Build-time scratch aliases (regions only written after the build):
    // hist/scanned in he (429KB each); bucketed = bufA (2*NNZ*4 = 25.6MB exact)
    int*      hist     = (int*)he;
    int*      scanned  = (int*)((char*)he + (512 << 10));
    unsigned* bucketed = (unsigned*)bufA;

    const int NB_SCAN = (NHT + 2047) / 2048;   // 53

    // ---- fused build: one histogram pass, one scan, one scatter ----
    part_hist_both<<<NBA, 256, 0, stream>>>(hid, hist);
    scan_blocks<<<NB_SCAN, 256, 0, stream>>>(hist, scanned, bsum, NHT);
    scan_bsums<<<1, 64, 0, stream>>>(bsum, NB_SCAN);
    scan_apply<<<(NHT + 255) / 256, 256, 0, stream>>>(scanned, bsum, NHT);
    part_scatter_both<<<NBA, 256, 0, stream>>>(hid, scanned, bucketed);
    bucket_build<0><<<NBUK0, 256, 0, stream>>>(bucketed, scanned, ptr1, Binv, list1, 0);
    bucket_build<1><<<NBUK1, 256, 0, stream>>>(bucketed, scanned + NH0, ptr2, Dinv, list2, NNZ);
    set_tail<<<1, 1, 0, stream>>>(ptr1, ptr2);

    // Layer 1: xW1 -> edge agg -> node agg (+b1, relu)
    gemm1_kernel<<<(N_NODES + 63) / 64, 256, 0, stream>>>(x, W1, bufA, N_NODES);
    seg_gather<0><<<(N_EDGES * 64) / 256, 256, 0, stream>>>(bufA, he, ptr1, list1, Binv, nullptr, N_EDGES, 0);
    seg_gather<1><<<(N_NODES * 64) / 256, 256, 0, stream>>>(he, bufB, ptr2, list2, Dinv, b1, N_NODES, 1);

    // Layer 2: edge agg -> node agg, then @W2 + b2 (associativity: A(hW2)=(Ah)W2)
    seg_gather<2><<<(N_EDGES * 64) / 256, 256, 0, stream>>>(bufB, he, ptr1, list1, Binv, nullptr, N_EDGES, 0);
    seg_gather<3><<<(N_NODES * 64) / 256, 256, 0, stream>>>(he, bufA, ptr2, list2, Dinv, nullptr, N_NODES, 0);
    gemm2_kernel<<<(N_NODES + 3) / 4, 256, 0, stream>>>(bufA, W2, b2, out, N_NODES);
}